// Round 1
// baseline (411.927 us; speedup 1.0000x reference)
//
#include <hip/hip_runtime.h>
#include <hip/hip_bf16.h>

typedef __bf16 bf16_t;
typedef bf16_t bf16x8 __attribute__((ext_vector_type(8)));
typedef float  f32x4  __attribute__((ext_vector_type(4)));

// Problem constants
#define NN  8
#define CC  256
#define T1C 16
#define HWC 784
#define T2C 64
#define VC  25
#define RELC 32

// ---------------------------------------------------------------------------
// w_iv fp32 -> bf16
__global__ void k_cvt_w(const float* __restrict__ w, bf16_t* __restrict__ wb) {
    int i = (blockIdx.x * 256 + threadIdx.x) * 4;
    float4 v = *(const float4*)(w + i);
    union { bf16_t b[4]; uint2 u; } o;
    o.b[0] = (__bf16)v.x; o.b[1] = (__bf16)v.y;
    o.b[2] = (__bf16)v.z; o.b[3] = (__bf16)v.w;
    *(uint2*)(wb + i) = o.u;
}

// ---------------------------------------------------------------------------
// motion [n,c,64,25] -> pool [n,c,16] (block mean over 4x25)
__global__ void k_mot(const float* __restrict__ mot, float* __restrict__ pool) {
    int bc = blockIdx.x;                 // n*C + c
    const float* src = mot + (long)bc * (T2C * VC);   // 1600 floats
    __shared__ float s[T2C * VC];
    for (int i = threadIdx.x; i < T2C * VC; i += 64) s[i] = src[i];
    __syncthreads();
    if (threadIdx.x < 16) {
        float a = 0.f;
        const float* p = s + threadIdx.x * 100;
        #pragma unroll 4
        for (int k = 0; k < 100; k++) a += p[k];
        pool[bc * 16 + threadIdx.x] = a * (1.0f / 100.0f);
    }
}

// ---------------------------------------------------------------------------
// image [n][c'][t][hw] fp32 -> imT [nl][t][hw][c'] bf16 ; fused mean partials
// grid: (14 hw-blocks of 56, 4 c'-blocks of 64, chunkN*16 (nl,j))
__global__ void k_transpose(const float* __restrict__ img, bf16_t* __restrict__ imT,
                            float* __restrict__ mean_raw, int n0) {
    int hwb = blockIdx.x, cb = blockIdx.y;
    int z = blockIdx.z; int nl = z >> 4, j = z & 15; int n = n0 + nl;
    int hw0 = hwb * 56, c0 = cb * 64;
    __shared__ __align__(16) bf16_t tile[56][68];
    __shared__ float ssum[64];
    int t = threadIdx.x;
    if (t < 64) ssum[t] = 0.f;
    __syncthreads();
    for (int fl = t; fl < 896; fl += 256) {
        int cl = fl / 14, f4 = fl % 14;
        float4 v = *(const float4*)(img + (((long)n * CC + c0 + cl) * T1C + j) * HWC + hw0 + f4 * 4);
        int hwl = f4 * 4;
        tile[hwl + 0][cl] = (__bf16)v.x;
        tile[hwl + 1][cl] = (__bf16)v.y;
        tile[hwl + 2][cl] = (__bf16)v.z;
        tile[hwl + 3][cl] = (__bf16)v.w;
        atomicAdd(&ssum[cl], v.x + v.y + v.z + v.w);
    }
    __syncthreads();
    if (t < 64) atomicAdd(mean_raw + ((long)n * CC + c0 + t) * T1C + j, ssum[t]);
    for (int fl = t; fl < 896; fl += 256) {
        int hwl = fl / 16, cg = fl % 16;
        ushort4 o = *(ushort4*)(&tile[hwl][cg * 4]);
        *(ushort4*)(imT + ((((long)nl * T1C + j) * HWC + hw0 + hwl) * CC + c0 + cg * 4)) = o;
    }
}

// ---------------------------------------------------------------------------
// att_t[n][c][j][i] = (sum_r w_att[c,r]*tanh(K[r,i]-Q[r,j]) + b_att[c])/16 + (i==j)
// one block per n
__global__ void k_att(const float* __restrict__ mean_raw, const float* __restrict__ pool,
                      const float* __restrict__ w_mq, const float* __restrict__ b_mq,
                      const float* __restrict__ w_iq, const float* __restrict__ b_iq,
                      const float* __restrict__ w_att, const float* __restrict__ b_att,
                      float* __restrict__ att_t, int n0) {
    int n = n0 + blockIdx.x;
    __shared__ float Qs[RELC * T1C], Ks[RELC * T1C], sc[RELC * T1C * T1C];
    int t = threadIdx.x;
    for (int o = t; o < 2 * RELC * T1C; o += 256) {
        int which = (o >= RELC * T1C);
        int rt = which ? o - RELC * T1C : o;
        int r = rt >> 4, tt = rt & 15;
        const float* wrow = which ? (w_mq + r * CC) : (w_iq + r * CC);
        const float* src  = which ? (pool + (long)n * CC * T1C + tt)
                                  : (mean_raw + (long)n * CC * T1C + tt);
        float scl = which ? 1.0f : (1.0f / 784.0f);
        float a = 0.f;
        for (int c = 0; c < CC; c++) a += wrow[c] * src[c * T1C];
        a = a * scl + (which ? b_mq[r] : b_iq[r]);
        (which ? Ks : Qs)[rt] = a;
    }
    __syncthreads();
    for (int o = t; o < RELC * T1C * T1C; o += 256) {
        int r = o >> 8, i = (o >> 4) & 15, j = o & 15;
        sc[o] = tanhf(Ks[r * 16 + i] - Qs[r * 16 + j]);
    }
    __syncthreads();
    int c = t;
    float wr[RELC];
    #pragma unroll
    for (int r = 0; r < RELC; r++) wr[r] = w_att[c * RELC + r];
    float bc = b_att[c];
    float* outp = att_t + ((long)n * CC + c) * 256;
    for (int j = 0; j < 16; j++) {
        for (int i = 0; i < 16; i++) {
            float a = bc;
            #pragma unroll
            for (int r = 0; r < RELC; r++) a += wr[r] * sc[r * 256 + i * 16 + j];
            a = a * (1.0f / 16.0f) + (i == j ? 1.0f : 0.0f);
            outp[j * 16 + i] = a;
        }
    }
}

// ---------------------------------------------------------------------------
// Main fused kernel: Vv = w_iv @ im (MFMA bf16), then y = att @ (Vv + b_iv)
// grid (98 hw-tiles of 8, chunkN), block 256 (4 waves)
__launch_bounds__(256, 2)
__global__ void k_main(const bf16_t* __restrict__ imT, const bf16_t* __restrict__ wb,
                       const float* __restrict__ att_t, const float* __restrict__ b_iv,
                       float* __restrict__ out, int n0) {
    const int COLS = 128, PITCH = 136, KHALF = 128;
    __shared__ __align__(16) bf16_t Bl[COLS * PITCH];   // 34816 B
    int t = threadIdx.x;
    int h = blockIdx.x;          // hw tile
    int nl = blockIdx.y; int n = n0 + nl;
    int hw0 = h * 8;
    int lane = t & 63, wave = t >> 6;
    int l15 = lane & 15, quad = lane >> 4;

    f32x4 acc[4][8];
    f32x4 zf = {0.f, 0.f, 0.f, 0.f};
    #pragma unroll
    for (int mt = 0; mt < 4; mt++)
        #pragma unroll
        for (int nt = 0; nt < 8; nt++) acc[mt][nt] = zf;

    const bf16_t* imTn = imT + (long)nl * T1C * HWC * CC;

    for (int kst = 0; kst < 2; ++kst) {
        __syncthreads();
        for (int s = t; s < 2048; s += 256) {
            int col = s >> 4, cc = s & 15;
            int j = col >> 3, hwl = col & 7;
            uint4 v = *(const uint4*)(imTn + ((long)j * HWC + hw0 + hwl) * CC + kst * KHALF + cc * 8);
            *(uint4*)(&Bl[col * PITCH + cc * 8]) = v;
        }
        __syncthreads();
        #pragma unroll
        for (int ks = 0; ks < 4; ++ks) {
            int ko = ks * 32 + quad * 8;
            bf16x8 a[4];
            #pragma unroll
            for (int mt = 0; mt < 4; ++mt)
                a[mt] = *(const bf16x8*)(wb + ((long)(wave * 64 + mt * 16 + l15)) * CC + kst * KHALF + ko);
            #pragma unroll
            for (int nt = 0; nt < 8; ++nt) {
                bf16x8 b = *(const bf16x8*)(&Bl[(nt * 16 + l15) * PITCH + ko]);
                #pragma unroll
                for (int mt = 0; mt < 4; ++mt)
                    acc[mt][nt] = __builtin_amdgcn_mfma_f32_16x16x32_bf16(a[mt], b, acc[mt][nt], 0, 0, 0);
            }
        }
    }
    __syncthreads();   // all waves done with Bl as B-tile

    // epilogue: per M-tile, Vv -> LDS (wave-private slice), apply att, store y
    float* Vbase = ((float*)Bl) + wave * (16 * 132);    // 2112 floats per wave
    const float* attn = att_t + (long)n * CC * 256;
    for (int mt = 0; mt < 4; ++mt) {
        #pragma unroll
        for (int nt = 0; nt < 8; ++nt) {
            #pragma unroll
            for (int r = 0; r < 4; r++) {
                int crow = quad * 4 + r;
                float biv = b_iv[wave * 64 + mt * 16 + crow];
                Vbase[crow * 132 + nt * 16 + l15] = acc[mt][nt][r] + biv;
            }
        }
        __syncthreads();   // uniform; also orders LDS write->read
        int cg = wave * 64 + mt * 16 + l15;
        const float* Vrow = Vbase + l15 * 132;
        const float* arow = attn + (long)cg * 256 + quad * 4;
        f32x4 y0[4], y1[4];
        #pragma unroll
        for (int ii = 0; ii < 4; ii++) { y0[ii] = zf; y1[ii] = zf; }
        #pragma unroll
        for (int j = 0; j < 16; j++) {
            f32x4 v0 = *(const f32x4*)(Vrow + j * 8);
            f32x4 v1 = *(const f32x4*)(Vrow + j * 8 + 4);
            f32x4 aa = *(const f32x4*)(arow + j * 16);
            #pragma unroll
            for (int ii = 0; ii < 4; ii++) {
                y0[ii] += aa[ii] * v0;
                y1[ii] += aa[ii] * v1;
            }
        }
        float* ob = out + ((long)n * CC + cg) * T1C * HWC + hw0;
        #pragma unroll
        for (int ii = 0; ii < 4; ii++) {
            int i = quad * 4 + ii;
            *(f32x4*)(ob + (long)i * HWC)     = y0[ii];
            *(f32x4*)(ob + (long)i * HWC + 4) = y1[ii];
        }
        __syncthreads();   // uniform; keep waves loosely in step before Vbase reuse
    }
}

// ---------------------------------------------------------------------------
extern "C" void kernel_launch(void* const* d_in, const int* in_sizes, int n_in,
                              void* d_out, int out_size, void* d_ws, size_t ws_size,
                              hipStream_t stream) {
    const float* image = (const float*)d_in[0];
    const float* motion = (const float*)d_in[1];
    const float* w_mq = (const float*)d_in[2];
    const float* b_mq = (const float*)d_in[3];
    const float* w_iq = (const float*)d_in[4];
    const float* b_iq = (const float*)d_in[5];
    const float* w_iv = (const float*)d_in[6];
    const float* b_iv = (const float*)d_in[7];
    const float* w_att = (const float*)d_in[8];
    const float* b_att = (const float*)d_in[9];
    float* out = (float*)d_out;

    const size_t IMT_PER_N = (size_t)T1C * HWC * CC * 2;   // 6,422,528 B
    const size_t W_BYTES = (size_t)CC * CC * 2;            // 131072
    const size_t MEAN_BYTES = (size_t)NN * CC * T1C * 4;   // 131072
    const size_t ATT_BYTES = (size_t)NN * CC * 256 * 4;    // 2097152
    size_t fixed = W_BYTES + MEAN_BYTES * 2 + ATT_BYTES;

    int chunkN = 8;
    while (chunkN > 1 && (size_t)chunkN * IMT_PER_N + fixed > ws_size) chunkN >>= 1;

    char* p = (char*)d_ws;
    bf16_t* imT = (bf16_t*)p;  p += (size_t)chunkN * IMT_PER_N;
    bf16_t* wbf = (bf16_t*)p;  p += W_BYTES;
    float* mean = (float*)p;   p += MEAN_BYTES;
    float* pool = (float*)p;   p += MEAN_BYTES;
    float* att  = (float*)p;

    hipMemsetAsync(mean, 0, MEAN_BYTES, stream);
    k_cvt_w<<<64, 256, 0, stream>>>(w_iv, wbf);
    k_mot<<<NN * CC, 64, 0, stream>>>(motion, pool);

    for (int n0 = 0; n0 < NN; n0 += chunkN) {
        k_transpose<<<dim3(14, 4, chunkN * 16), 256, 0, stream>>>(image, imT, mean, n0);
        k_att<<<chunkN, 256, 0, stream>>>(mean, pool, w_mq, b_mq, w_iq, b_iq,
                                          w_att, b_att, att, n0);
        k_main<<<dim3(98, chunkN), 256, 0, stream>>>(imT, wbf, att, b_iv, out, n0);
    }
}

// Round 2
// 380.077 us; speedup vs baseline: 1.0838x; 1.0838x over previous
//
#include <hip/hip_runtime.h>
#include <hip/hip_bf16.h>

typedef __bf16 bf16_t;
typedef bf16_t bf16x8 __attribute__((ext_vector_type(8)));
typedef float  f32x4  __attribute__((ext_vector_type(4)));

// Problem constants
#define NN  8
#define CC  256
#define T1C 16
#define HWC 784
#define T2C 64
#define VC  25
#define RELC 32

// ---------------------------------------------------------------------------
// w_iv fp32 -> bf16
__global__ void k_cvt_w(const float* __restrict__ w, bf16_t* __restrict__ wb) {
    int i = (blockIdx.x * 256 + threadIdx.x) * 4;
    float4 v = *(const float4*)(w + i);
    union { bf16_t b[4]; uint2 u; } o;
    o.b[0] = (__bf16)v.x; o.b[1] = (__bf16)v.y;
    o.b[2] = (__bf16)v.z; o.b[3] = (__bf16)v.w;
    *(uint2*)(wb + i) = o.u;
}

// ---------------------------------------------------------------------------
// motion [n,c,64,25] -> pool [n,c,16] (block mean over 4x25)
__global__ void k_mot(const float* __restrict__ mot, float* __restrict__ pool) {
    int bc = blockIdx.x;                 // n*C + c
    const float* src = mot + (long)bc * (T2C * VC);   // 1600 floats
    __shared__ float s[T2C * VC];
    for (int i = threadIdx.x; i < T2C * VC; i += 64) s[i] = src[i];
    __syncthreads();
    if (threadIdx.x < 16) {
        float a = 0.f;
        const float* p = s + threadIdx.x * 100;
        #pragma unroll 4
        for (int k = 0; k < 100; k++) a += p[k];
        pool[bc * 16 + threadIdx.x] = a * (1.0f / 100.0f);
    }
}

// ---------------------------------------------------------------------------
// image [n][c'][t][hw] fp32 -> imT [nl][t][hw][c'] bf16 ; fused mean partials
// grid: (14 hw-blocks of 56, 4 c'-blocks of 64, chunkN*16 (nl,j))
// mean via register partials + shfl reduce (no LDS atomics)
__global__ void k_transpose(const float* __restrict__ img, bf16_t* __restrict__ imT,
                            float* __restrict__ mean_raw, int n0) {
    int hwb = blockIdx.x, cb = blockIdx.y;
    int z = blockIdx.z; int nl = z >> 4, j = z & 15; int n = n0 + nl;
    int hw0 = hwb * 56, c0 = cb * 64;
    __shared__ __align__(16) bf16_t tile[56][68];
    int t = threadIdx.x;
    int f4 = t & 15, cl0 = t >> 4;       // cl0 in 0..15
    float psum[4];
    #pragma unroll
    for (int k = 0; k < 4; k++) {
        int cl = cl0 + 16 * k;
        float4 v = {0.f, 0.f, 0.f, 0.f};
        if (f4 < 14)
            v = *(const float4*)(img + (((long)n * CC + c0 + cl) * T1C + j) * HWC + hw0 + f4 * 4);
        psum[k] = v.x + v.y + v.z + v.w;
        if (f4 < 14) {
            int hwl = f4 * 4;
            tile[hwl + 0][cl] = (__bf16)v.x;
            tile[hwl + 1][cl] = (__bf16)v.y;
            tile[hwl + 2][cl] = (__bf16)v.z;
            tile[hwl + 3][cl] = (__bf16)v.w;
        }
    }
    #pragma unroll
    for (int k = 0; k < 4; k++) {
        float s = psum[k];
        s += __shfl_xor(s, 1); s += __shfl_xor(s, 2);
        s += __shfl_xor(s, 4); s += __shfl_xor(s, 8);
        psum[k] = s;
    }
    if (f4 == 0) {
        #pragma unroll
        for (int k = 0; k < 4; k++)
            atomicAdd(mean_raw + ((long)n * CC + c0 + cl0 + 16 * k) * T1C + j, psum[k]);
    }
    __syncthreads();
    for (int fl = t; fl < 896; fl += 256) {
        int hwl = fl >> 4, cg = fl & 15;
        ushort4 o = *(ushort4*)(&tile[hwl][cg * 4]);
        *(ushort4*)(imT + ((((long)nl * T1C + j) * HWC + hw0 + hwl) * CC + c0 + cg * 4)) = o;
    }
}

// ---------------------------------------------------------------------------
// Q/K + scores. grid chunkN, block 256.
// scoresG[n][r*256 + j*16 + i] = tanh(K[r,i] - Q[r,j])
__global__ void k_qk(const float* __restrict__ mean_raw, const float* __restrict__ pool,
                     const float* __restrict__ w_mq, const float* __restrict__ b_mq,
                     const float* __restrict__ w_iq, const float* __restrict__ b_iq,
                     float* __restrict__ scoresG, int n0) {
    int n = n0 + blockIdx.x;
    const int PQ = 260;                  // pad: lane-stride 260 -> 2-way banks (free)
    __shared__ float meanT[16 * PQ];     // [t][c]
    __shared__ float poolT[16 * PQ];
    __shared__ float Qs[512], Ks[512];   // [r*16+t]
    int t = threadIdx.x;
    {
        const float* mr = mean_raw + ((long)n * CC + t) * 16;
        const float* pr = pool + ((long)n * CC + t) * 16;
        #pragma unroll
        for (int tt = 0; tt < 16; tt++) {
            meanT[tt * PQ + t] = mr[tt] * (1.0f / 784.0f);
            poolT[tt * PQ + t] = pr[tt];
        }
    }
    __syncthreads();
    for (int item = t; item < 1024; item += 256) {
        int which = item >> 9;           // 0: Q (img mean), 1: K (motion pool)
        int rt = item & 511;
        int r = rt >> 4, tt = rt & 15;
        const float* wrow = which ? (w_mq + r * CC) : (w_iq + r * CC);
        const float* src = (which ? poolT : meanT) + tt * PQ;
        float a = 0.f;
        #pragma unroll 8
        for (int c = 0; c < CC; c++) a += wrow[c] * src[c];
        a += which ? b_mq[r] : b_iq[r];
        (which ? Ks : Qs)[rt] = a;
    }
    __syncthreads();
    float* sg = scoresG + (long)n * 8192;
    for (int o = t; o < 8192; o += 256) {
        int r = o >> 8, jj = (o >> 4) & 15, ii = o & 15;
        sg[o] = tanhf(Ks[r * 16 + ii] - Qs[r * 16 + jj]);
    }
}

// ---------------------------------------------------------------------------
// att_t[n][c][j*16+i] = (sum_r w_att[c,r]*scores[r,i,j] + b_att[c])/16 + (i==j)
// grid (chunkN, 16), block 256 = 16 c x 16 i
__global__ void k_att2(const float* __restrict__ scoresG, const float* __restrict__ w_att,
                       const float* __restrict__ b_att, float* __restrict__ att_t, int n0) {
    int n = n0 + blockIdx.x;
    int cb = blockIdx.y;
    __shared__ float sc[8192];           // [r][j][i]
    __shared__ float wa[16][33];
    int t = threadIdx.x;
    const float* sg = scoresG + (long)n * 8192;
    for (int o = t; o < 8192; o += 256) sc[o] = sg[o];
    for (int o = t; o < 512; o += 256) {
        int cl = o >> 5, r = o & 31;
        wa[cl][r] = w_att[(cb * 16 + cl) * RELC + r];
    }
    __syncthreads();
    int cl = t >> 4, ii = t & 15;
    int c = cb * 16 + cl;
    float bc = b_att[c];
    float wr[RELC];
    #pragma unroll
    for (int r = 0; r < RELC; r++) wr[r] = wa[cl][r];
    float* outp = att_t + ((long)n * CC + c) * 256;
    #pragma unroll
    for (int j = 0; j < 16; j++) {
        float a = bc;
        #pragma unroll
        for (int r = 0; r < RELC; r++) a += wr[r] * sc[r * 256 + j * 16 + ii];
        outp[j * 16 + ii] = a * (1.0f / 16.0f) + (ii == j ? 1.0f : 0.0f);
    }
}

// ---------------------------------------------------------------------------
// Main fused kernel: Vv = w_iv @ im (MFMA bf16), then y = att @ (Vv + b_iv)
// grid (98 hw-tiles of 8, chunkN), block 256 (4 waves)
// Epilogue is barrier-free: each wave's Vv slice in LDS is wave-private.
__launch_bounds__(256, 2)
__global__ void k_main(const bf16_t* __restrict__ imT, const bf16_t* __restrict__ wb,
                       const float* __restrict__ att_t, const float* __restrict__ b_iv,
                       float* __restrict__ out, int n0) {
    const int PITCH = 136, KHALF = 128;
    __shared__ __align__(16) bf16_t Bl[128 * PITCH];   // 34816 B
    int t = threadIdx.x;
    int h = blockIdx.x;          // hw tile
    int nl = blockIdx.y; int n = n0 + nl;
    int hw0 = h * 8;
    int lane = t & 63, wave = t >> 6;
    int l15 = lane & 15, quad = lane >> 4;

    f32x4 acc[4][8];
    f32x4 zf = {0.f, 0.f, 0.f, 0.f};
    #pragma unroll
    for (int mt = 0; mt < 4; mt++)
        #pragma unroll
        for (int nt = 0; nt < 8; nt++) acc[mt][nt] = zf;

    const bf16_t* imTn = imT + (long)nl * T1C * HWC * CC;

    for (int kst = 0; kst < 2; ++kst) {
        __syncthreads();
        for (int s = t; s < 2048; s += 256) {
            int col = s >> 4, cc = s & 15;
            int j = col >> 3, hwl = col & 7;
            uint4 v = *(const uint4*)(imTn + ((long)j * HWC + hw0 + hwl) * CC + kst * KHALF + cc * 8);
            *(uint4*)(&Bl[col * PITCH + cc * 8]) = v;
        }
        __syncthreads();
        #pragma unroll
        for (int ks = 0; ks < 4; ++ks) {
            int ko = ks * 32 + quad * 8;
            bf16x8 a[4];
            #pragma unroll
            for (int mt = 0; mt < 4; ++mt)
                a[mt] = *(const bf16x8*)(wb + ((long)(wave * 64 + mt * 16 + l15)) * CC + kst * KHALF + ko);
            #pragma unroll
            for (int nt = 0; nt < 8; ++nt) {
                bf16x8 b = *(const bf16x8*)(&Bl[(nt * 16 + l15) * PITCH + ko]);
                #pragma unroll
                for (int mt = 0; mt < 4; ++mt)
                    acc[mt][nt] = __builtin_amdgcn_mfma_f32_16x16x32_bf16(a[mt], b, acc[mt][nt], 0, 0, 0);
            }
        }
    }
    __syncthreads();   // all waves done reading Bl as B-tile; Vv slices reuse it

    // epilogue: per M-tile, Vv -> wave-private LDS slice, apply att, store y.
    // No barriers: intra-wave ds ordering (lgkmcnt) is sufficient.
    float* Vbase = ((float*)Bl) + wave * (16 * 132);    // 2112 floats per wave
    const float* attn = att_t + (long)n * CC * 256;
    for (int mt = 0; mt < 4; ++mt) {
        #pragma unroll
        for (int nt = 0; nt < 8; ++nt) {
            #pragma unroll
            for (int r = 0; r < 4; r++) {
                int crow = quad * 4 + r;
                float biv = b_iv[wave * 64 + mt * 16 + crow];
                Vbase[crow * 132 + nt * 16 + l15] = acc[mt][nt][r] + biv;
            }
        }
        int cg = wave * 64 + mt * 16 + l15;
        const float* Vrow = Vbase + l15 * 132;
        const float* arow = attn + (long)cg * 256 + quad * 4;
        f32x4 y0[4], y1[4];
        #pragma unroll
        for (int ii = 0; ii < 4; ii++) { y0[ii] = zf; y1[ii] = zf; }
        #pragma unroll
        for (int j = 0; j < 16; j++) {
            f32x4 v0 = *(const f32x4*)(Vrow + j * 8);
            f32x4 v1 = *(const f32x4*)(Vrow + j * 8 + 4);
            f32x4 aa = *(const f32x4*)(arow + j * 16);
            #pragma unroll
            for (int ii = 0; ii < 4; ii++) {
                y0[ii] += aa[ii] * v0;
                y1[ii] += aa[ii] * v1;
            }
        }
        float* ob = out + ((long)n * CC + cg) * T1C * HWC + hw0;
        #pragma unroll
        for (int ii = 0; ii < 4; ii++) {
            int i = quad * 4 + ii;
            *(f32x4*)(ob + (long)i * HWC)     = y0[ii];
            *(f32x4*)(ob + (long)i * HWC + 4) = y1[ii];
        }
    }
}

// ---------------------------------------------------------------------------
extern "C" void kernel_launch(void* const* d_in, const int* in_sizes, int n_in,
                              void* d_out, int out_size, void* d_ws, size_t ws_size,
                              hipStream_t stream) {
    const float* image = (const float*)d_in[0];
    const float* motion = (const float*)d_in[1];
    const float* w_mq = (const float*)d_in[2];
    const float* b_mq = (const float*)d_in[3];
    const float* w_iq = (const float*)d_in[4];
    const float* b_iq = (const float*)d_in[5];
    const float* w_iv = (const float*)d_in[6];
    const float* b_iv = (const float*)d_in[7];
    const float* w_att = (const float*)d_in[8];
    const float* b_att = (const float*)d_in[9];
    float* out = (float*)d_out;

    const size_t IMT_PER_N = (size_t)T1C * HWC * CC * 2;   // 6,422,528 B
    const size_t W_BYTES = (size_t)CC * CC * 2;            // 131072
    const size_t MEAN_BYTES = (size_t)NN * CC * T1C * 4;   // 131072
    const size_t ATT_BYTES = (size_t)NN * CC * 256 * 4;    // 2097152
    const size_t SC_BYTES = (size_t)NN * 8192 * 4;         // 262144
    size_t fixed = W_BYTES + MEAN_BYTES * 2 + ATT_BYTES + SC_BYTES;

    int chunkN = 8;
    while (chunkN > 1 && (size_t)chunkN * IMT_PER_N + fixed > ws_size) chunkN >>= 1;

    char* p = (char*)d_ws;
    bf16_t* imT = (bf16_t*)p;  p += (size_t)chunkN * IMT_PER_N;
    bf16_t* wbf = (bf16_t*)p;  p += W_BYTES;
    float* mean = (float*)p;   p += MEAN_BYTES;
    float* pool = (float*)p;   p += MEAN_BYTES;
    float* att  = (float*)p;   p += ATT_BYTES;
    float* scoresG = (float*)p;

    hipMemsetAsync(mean, 0, MEAN_BYTES, stream);
    k_cvt_w<<<64, 256, 0, stream>>>(w_iv, wbf);
    k_mot<<<NN * CC, 64, 0, stream>>>(motion, pool);

    for (int n0 = 0; n0 < NN; n0 += chunkN) {
        k_transpose<<<dim3(14, 4, chunkN * 16), 256, 0, stream>>>(image, imT, mean, n0);
        k_qk<<<chunkN, 256, 0, stream>>>(mean, pool, w_mq, b_mq, w_iq, b_iq, scoresG, n0);
        k_att2<<<dim3(chunkN, 16), 256, 0, stream>>>(scoresG, w_att, b_att, att, n0);
        k_main<<<dim3(98, chunkN), 256, 0, stream>>>(imT, wbf, att, b_iv, out, n0);
    }
}